// Round 11
// baseline (290.789 us; speedup 1.0000x reference)
//
#include <hip/hip_runtime.h>
#include <hip/hip_bf16.h>
#include <type_traits>

// ---------- types ----------
typedef __attribute__((ext_vector_type(8))) short short8;   // 8 bf16 (4 VGPRs) MFMA A/B frag
typedef __attribute__((ext_vector_type(4))) float f32x4;    // MFMA C/D frag / float4
typedef __attribute__((ext_vector_type(8))) unsigned short u16x8;

static __device__ __forceinline__ unsigned short f2b(float f) {
    unsigned int v = __float_as_uint(f);
    unsigned int r = (v + 0x7FFFu + ((v >> 16) & 1u)) >> 16;   // RNE
    return (unsigned short)r;
}
static __device__ __forceinline__ float b2f(unsigned short u) {
    return __uint_as_float(((unsigned int)u) << 16);
}

// ---------- fused: all-weights transpose+cast  ||  dst-degree histogram ----------
__global__ void k_pre(const float* __restrict__ w1, unsigned short* __restrict__ t1,
                      const float* __restrict__ w2, unsigned short* __restrict__ t2,
                      const float* __restrict__ w3, unsigned short* __restrict__ t3,
                      int K1, int N1, int K2, int N2, int K3, int N3,
                      const int* __restrict__ dst, int* __restrict__ cnt, int E, int tblk) {
    if ((int)blockIdx.x < tblk) {
        int i = blockIdx.x * 256 + threadIdx.x;
        int n1 = K1 * N1, n2 = K2 * N2, n3 = K3 * N3;
        if (i < n1) {
            int k = i / N1, n = i % N1;
            t1[n * K1 + k] = f2b(w1[i]);
        } else if (i < n1 + n2) {
            int j = i - n1, k = j / N2, n = j % N2;
            t2[n * K2 + k] = f2b(w2[j]);
        } else if (i < n1 + n2 + n3) {
            int j = i - n1 - n2, k = j / N3, n = j % N3;
            t3[n * K3 + k] = f2b(w3[j]);
        }
    } else {
        int e = (blockIdx.x - tblk) * 256 + threadIdx.x;
        if (e < E) atomicAdd(&cnt[dst[e]], 1);
    }
}

// per-node segment allocation: wave-scan of (cnt+1) + one atomicAdd per wave.
// Places the self-loop at slot 0; fill[i] holds the ABSOLUTE next write slot (beg+1).
__global__ void k_assign(const int* __restrict__ cnt, int* __restrict__ begptr,
                         int* __restrict__ colidx, int* __restrict__ fill,
                         int* __restrict__ cursor, int n) {
    int i = blockIdx.x * 256 + threadIdx.x;
    int lane = threadIdx.x & 63;
    int c = (i < n) ? cnt[i] + 1 : 0;
    int s = c;  // inclusive wave scan
#pragma unroll
    for (int off = 1; off < 64; off <<= 1) {
        int v = __shfl_up(s, off);
        if (lane >= off) s += v;
    }
    int wavesum = __shfl(s, 63);
    int base = 0;
    if (lane == 63) base = atomicAdd(cursor, wavesum);
    base = __shfl(base, 63);
    int beg = base + s - c;
    if (i < n) { begptr[i] = beg; colidx[beg] = i; fill[i] = beg + 1; }
}

// ---------- MFMA GEMM body (BK=64) + fused attention logits ----------
template<int NC, typename AT>
static __device__ __forceinline__ void gemm_body(const AT* __restrict__ A,
                                                 const unsigned short* __restrict__ Bt,
                                                 unsigned short* __restrict__ H,
                                                 const float* __restrict__ asrc,
                                                 const float* __restrict__ adst,
                                                 float* __restrict__ als,
                                                 float* __restrict__ ald,
                                                 int K, int blk) {
    __shared__ unsigned short As[64][72];   // 64 k-cols + 8 pad
    __shared__ unsigned short Bs[NC][72];
    __shared__ float sps[64], spd[64];
    const int tid  = threadIdx.x;
    const int lane = tid & 63;
    const int wv   = tid >> 6;
    const int rowBase = blk * 64;
    const int quad = lane >> 4;
    const int l16  = lane & 15;
    constexpr int CG = NC / 32;             // col-frags per wave
    const int wrow = (wv & 1) * 32;
    const int wcol = (wv >> 1) * (NC / 2);
    f32x4 acc[2][CG] = {};

    if (tid < 64) { sps[tid] = 0.f; spd[tid] = 0.f; }

    const int ar = tid >> 2;                // A staging row 0..63
    const int ak = (tid & 3) * 16;          // A staging k-chunk (16 elems)

    for (int kk = 0; kk < K; kk += 64) {
        // stage A (16 elems/thread)
        if constexpr (std::is_same_v<AT, float>) {
            const float* ap = A + (size_t)(rowBase + ar) * K + kk + ak;
            f32x4 a0 = *(const f32x4*)ap;
            f32x4 a1 = *(const f32x4*)(ap + 4);
            f32x4 a2 = *(const f32x4*)(ap + 8);
            f32x4 a3 = *(const f32x4*)(ap + 12);
            short8 s0, s1;
#pragma unroll
            for (int v = 0; v < 4; v++) {
                s0[v] = (short)f2b(a0[v]); s0[4 + v] = (short)f2b(a1[v]);
                s1[v] = (short)f2b(a2[v]); s1[4 + v] = (short)f2b(a3[v]);
            }
            *(short8*)&As[ar][ak] = s0;
            *(short8*)&As[ar][ak + 8] = s1;
        } else {
            const unsigned short* ap = A + (size_t)(rowBase + ar) * K + kk + ak;
            *(short8*)&As[ar][ak]     = *(const short8*)ap;
            *(short8*)&As[ar][ak + 8] = *(const short8*)(ap + 8);
        }
        // stage B (chunks of 16)
#pragma unroll
        for (int c = tid; c < NC * 4; c += 256) {
            int br = c >> 2, bk = (c & 3) * 16;
            const unsigned short* bp = Bt + (size_t)br * K + kk + bk;
            *(short8*)&Bs[br][bk]     = *(const short8*)bp;
            *(short8*)&Bs[br][bk + 8] = *(const short8*)(bp + 8);
        }
        __syncthreads();
#pragma unroll
        for (int s = 0; s < 2; s++) {
            short8 af0 = *(const short8*)&As[wrow + l16][s * 32 + quad * 8];
            short8 af1 = *(const short8*)&As[wrow + 16 + l16][s * 32 + quad * 8];
#pragma unroll
            for (int cg = 0; cg < CG; cg++) {
                short8 bf = *(const short8*)&Bs[wcol + cg * 16 + l16][s * 32 + quad * 8];
                acc[0][cg] = __builtin_amdgcn_mfma_f32_16x16x32_bf16(af0, bf, acc[0][cg], 0, 0, 0);
                acc[1][cg] = __builtin_amdgcn_mfma_f32_16x16x32_bf16(af1, bf, acc[1][cg], 0, 0, 0);
            }
        }
        __syncthreads();
    }

    // epilogue: store bf16 H + fused partial logits
    float avs[CG], avd[CG];
#pragma unroll
    for (int cg = 0; cg < CG; cg++) {
        int gcol = wcol + cg * 16 + l16;
        avs[cg] = asrc[gcol];
        avd[cg] = adst[gcol];
#pragma unroll
        for (int rg = 0; rg < 2; rg++)
#pragma unroll
            for (int r = 0; r < 4; r++) {
                int grow = rowBase + wrow + rg * 16 + quad * 4 + r;
                H[(size_t)grow * NC + gcol] = f2b(acc[rg][cg][r]);
            }
    }
#pragma unroll
    for (int rg = 0; rg < 2; rg++)
#pragma unroll
        for (int r = 0; r < 4; r++) {
            float ps = 0.f, pd = 0.f;
#pragma unroll
            for (int cg = 0; cg < CG; cg++) { ps += acc[rg][cg][r] * avs[cg]; pd += acc[rg][cg][r] * avd[cg]; }
#pragma unroll
            for (int off = 8; off; off >>= 1) { ps += __shfl_xor(ps, off); pd += __shfl_xor(pd, off); }
            if (l16 == 0) {
                int lrow = wrow + rg * 16 + quad * 4 + r;
                atomicAdd(&sps[lrow], ps);
                atomicAdd(&spd[lrow], pd);
            }
        }
    __syncthreads();
    if (tid < 64) { als[rowBase + tid] = sps[tid]; ald[rowBase + tid] = spd[tid]; }
}

// plain GEMM kernel (layers 2,3)
template<int NC, typename AT>
__global__ __launch_bounds__(256) void k_gemm(const AT* __restrict__ A,
                                              const unsigned short* __restrict__ Bt,
                                              unsigned short* __restrict__ H,
                                              const float* __restrict__ asrc,
                                              const float* __restrict__ adst,
                                              float* __restrict__ als,
                                              float* __restrict__ ald, int K) {
    gemm_body<NC, AT>(A, Bt, H, asrc, adst, als, ald, K, blockIdx.x);
}

// fused: layer-1 GEMM || edge scatter
template<int NC, typename AT>
__global__ __launch_bounds__(256) void k_gemm_scatter(const AT* __restrict__ A,
                                                      const unsigned short* __restrict__ Bt,
                                                      unsigned short* __restrict__ H,
                                                      const float* __restrict__ asrc,
                                                      const float* __restrict__ adst,
                                                      float* __restrict__ als,
                                                      float* __restrict__ ald, int K, int gblk,
                                                      const int* __restrict__ src,
                                                      const int* __restrict__ dst,
                                                      int* __restrict__ fill,
                                                      int* __restrict__ colidx, int E) {
    if ((int)blockIdx.x < gblk) {
        gemm_body<NC, AT>(A, Bt, H, asrc, adst, als, ald, K, blockIdx.x);
    } else {
        int e = (blockIdx.x - gblk) * 256 + threadIdx.x;
        if (e < E) {
            int s = src[e], d = dst[e];
            int pos = atomicAdd(&fill[d], 1);
            colidx[pos] = s;
        }
    }
}

// ---------- edge softmax + weighted aggregation: ONE NODE PER 16-LANE QUARTER ----------
// 4 nodes/wave, 16 nodes/block. Pass 3 unrolled x2: both guarded edge-loads issue
// before either FMA block (doubles in-flight bytes — MLP-limited regime).
// No max-subtraction (logits O(1), fp32-safe).
template<int DOUT, bool RELU, typename OutT>
__global__ __launch_bounds__(256) void k_edge(const unsigned short* __restrict__ h,
                                              const float* __restrict__ als,
                                              const float* __restrict__ ald,
                                              const int* __restrict__ begptr,
                                              const int* __restrict__ cnt,
                                              const int* __restrict__ colidx,
                                              const float* __restrict__ bias,
                                              OutT* __restrict__ out, int N) {
    int node = blockIdx.x * 16 + (threadIdx.x >> 4);
    if (node >= N) return;
    int lane  = threadIdx.x & 63;
    int l16   = lane & 15;
    int qbase = lane & 48;                  // quarter base within wave
    int beg = begptr[node];
    int deg = cnt[node] + 1;                // + self-loop
    float aldi = ald[node];

    // phase 1: exp + sum over this quarter's 16 lanes (first 16 edges cached)
    float ex_lane = 0.f;
    int   s_lane  = 0;
    float dsum = 0.f;
    for (int j = l16; j < deg; j += 16) {
        int s = colidx[beg + j];
        float e = als[s] + aldi;
        e = e > 0.f ? e : 0.2f * e;
        float ex = __expf(e);
        if (j < 16) { ex_lane = ex; s_lane = s; }
        dsum += ex;
    }
#pragma unroll
    for (int off = 8; off; off >>= 1) dsum += __shfl_xor(dsum, off, 16);
    float inv = 1.0f / dsum;
    float w_lane = ex_lane * inv;           // lanes >= deg carry 0

    // wave-uniform loop bounds (max over the wave's 4 quarters)
    int d16 = deg < 16 ? deg : 16;
    int m16 = d16;
    m16 = max(m16, __shfl_xor(m16, 16));
    m16 = max(m16, __shfl_xor(m16, 32));
    int mall = deg;
    mall = max(mall, __shfl_xor(mall, 16));
    mall = max(mall, __shfl_xor(mall, 32));

    constexpr int QV  = DOUT / 16;          // dims per lane (16 @ 256, 8 @ 128)
    constexpr int NC8 = QV / 8;             // u16x8 chunks per lane (2 or 1)
    const size_t dimOff = (size_t)l16 * QV;
    float acc[QV] = {};

    // pass 3: unroll x2 — both loads in flight before the FMAs
    for (int t = 0; t < m16; t += 2) {
        float wj0 = __shfl(w_lane, qbase + t);
        int   sj0 = __shfl(s_lane, qbase + t);
        float wj1 = 0.f;
        int   sj1 = 0;
        if (t + 1 < m16) {                  // wave-uniform condition
            wj1 = __shfl(w_lane, qbase + t + 1);
            sj1 = __shfl(s_lane, qbase + t + 1);
        }
        bool p0 = wj0 != 0.f;
        bool p1 = wj1 != 0.f;
        u16x8 c0[NC8], c1[NC8];
        if (p0) {
            const unsigned short* hp = h + (size_t)sj0 * DOUT + dimOff;
#pragma unroll
            for (int u = 0; u < NC8; u++) c0[u] = *(const u16x8*)(hp + 8 * u);
        }
        if (p1) {
            const unsigned short* hp = h + (size_t)sj1 * DOUT + dimOff;
#pragma unroll
            for (int u = 0; u < NC8; u++) c1[u] = *(const u16x8*)(hp + 8 * u);
        }
        if (p0) {
#pragma unroll
            for (int u = 0; u < NC8; u++)
#pragma unroll
                for (int v = 0; v < 8; v++) acc[8 * u + v] += wj0 * b2f(c0[u][v]);
        }
        if (p1) {
#pragma unroll
            for (int u = 0; u < NC8; u++)
#pragma unroll
                for (int v = 0; v < 8; v++) acc[8 * u + v] += wj1 * b2f(c1[u][v]);
        }
    }
    for (int t = 16; t < mall; t++) {           // deg>16 tail (~5% of nodes): recompute w
        if (t < deg) {
            int sj = colidx[beg + t];
            float e = als[sj] + aldi;
            e = e > 0.f ? e : 0.2f * e;
            float wj = __expf(e) * inv;
            const unsigned short* hp = h + (size_t)sj * DOUT + dimOff;
#pragma unroll
            for (int u = 0; u < NC8; u++) {
                u16x8 c = *(const u16x8*)(hp + 8 * u);
#pragma unroll
                for (int v = 0; v < 8; v++) acc[8 * u + v] += wj * b2f(c[v]);
            }
        }
    }

    // epilogue: every lane writes its QV dims of its quarter's node
    if constexpr (std::is_same_v<OutT, float>) {
        float* op = out + (size_t)node * DOUT + dimOff;
#pragma unroll
        for (int u = 0; u < QV / 4; u++) {
            f32x4 bv = *(const f32x4*)(bias + dimOff + 4 * u);
            f32x4 ov;
#pragma unroll
            for (int v = 0; v < 4; v++) {
                float val = acc[4 * u + v] + bv[v];
                if (RELU) val = fmaxf(val, 0.f);
                ov[v] = val;
            }
            *(f32x4*)(op + 4 * u) = ov;
        }
    } else {
        unsigned short* op = out + (size_t)node * DOUT + dimOff;
#pragma unroll
        for (int u = 0; u < NC8; u++) {
            u16x8 ov;
#pragma unroll
            for (int v = 0; v < 8; v++) {
                float val = acc[8 * u + v] + bias[dimOff + 8 * u + v];
                if (RELU) val = fmaxf(val, 0.f);
                ov[v] = f2b(val);
            }
            *(u16x8*)(op + 8 * u) = ov;
        }
    }
}

// ---------- launch ----------
extern "C" void kernel_launch(void* const* d_in, const int* in_sizes, int n_in,
                              void* d_out, int out_size, void* d_ws, size_t ws_size,
                              hipStream_t stream) {
    const int DIN = 128, DH = 256, DOUT = 128;
    const int N = in_sizes[0] / DIN;        // 40000
    const int E = in_sizes[1] / 2;          // 400000

    const float* x   = (const float*)d_in[0];
    const int*   ei  = (const int*)d_in[1];
    const float* W1  = (const float*)d_in[3];
    const float* as1 = (const float*)d_in[4];
    const float* ad1 = (const float*)d_in[5];
    const float* b1  = (const float*)d_in[6];
    const float* W2  = (const float*)d_in[7];
    const float* as2 = (const float*)d_in[8];
    const float* ad2 = (const float*)d_in[9];
    const float* b2  = (const float*)d_in[10];
    const float* W3  = (const float*)d_in[11];
    const float* as3 = (const float*)d_in[12];
    const float* ad3 = (const float*)d_in[13];
    const float* b3  = (const float*)d_in[14];
    float* outp = (float*)d_out;

    // workspace carve
    char* ws = (char*)d_ws;
    size_t off = 0;
    auto carve = [&](size_t bytes) { char* p = ws + off; off = (off + bytes + 255) & ~(size_t)255; return p; };
    unsigned short* hbuf = (unsigned short*)carve((size_t)N * DH * 2);  // 20 MB bf16
    unsigned short* gbuf = (unsigned short*)carve((size_t)N * DH * 2);  // 20 MB bf16
    float* als  = (float*)carve((size_t)N * 4);
    float* ald  = (float*)carve((size_t)N * 4);
    unsigned short* wt1 = (unsigned short*)carve((size_t)DIN * DH * 2);
    unsigned short* wt2 = (unsigned short*)carve((size_t)DH * DH * 2);
    unsigned short* wt3 = (unsigned short*)carve((size_t)DH * DOUT * 2);
    int* cnt    = (int*)carve((size_t)N * 4);
    int* cursor = (int*)carve(256);
    int* begptr = (int*)carve((size_t)N * 4);
    int* fill   = (int*)carve((size_t)N * 4);
    int* colidx = (int*)carve((size_t)(E + N) * 4);
    (void)ws_size; (void)n_in; (void)out_size;

    const int* e_src = ei;
    const int* e_dst = ei + E;

    // zero cnt..cursor in one async memset (allowed under graph capture)
    hipMemsetAsync(cnt, 0, (size_t)((char*)cursor - (char*)cnt) + 4, stream);

    const int tot    = DIN * DH + DH * DH + DH * DOUT;   // transpose elements
    const int tblk   = (tot + 255) / 256;
    const int eblk   = (E + 255) / 256;
    const int nblk16 = (N + 15) / 16;
    const int mblk   = N / 64;

    // transpose+cast all weights  ||  degree histogram
    k_pre<<<tblk + eblk, 256, 0, stream>>>(W1, wt1, W2, wt2, W3, wt3,
                                           DIN, DH, DH, DH, DH, DOUT,
                                           e_dst, cnt, E, tblk);
    k_assign<<<(N + 255) / 256, 256, 0, stream>>>(cnt, begptr, colidx, fill, cursor, N);

    // ---- layer 1 GEMM || edge scatter ----
    k_gemm_scatter<256, float><<<mblk + eblk, 256, 0, stream>>>(
        x, wt1, hbuf, as1, ad1, als, ald, DIN, mblk,
        e_src, e_dst, fill, colidx, E);
    k_edge<256, true, unsigned short><<<nblk16, 256, 0, stream>>>(hbuf, als, ald, begptr, cnt, colidx, b1, gbuf, N);

    // ---- layer 2: g[N,256] @ W2[256,256] ----
    k_gemm<256, unsigned short><<<mblk, 256, 0, stream>>>(gbuf, wt2, hbuf, as2, ad2, als, ald, DH);
    k_edge<256, true, unsigned short><<<nblk16, 256, 0, stream>>>(hbuf, als, ald, begptr, cnt, colidx, b2, gbuf, N);

    // ---- layer 3: g[N,256] @ W3[256,128] ----
    k_gemm<128, unsigned short><<<mblk, 256, 0, stream>>>(gbuf, wt3, hbuf, as3, ad3, als, ald, DH);
    k_edge<128, false, float><<<nblk16, 256, 0, stream>>>(hbuf, als, ald, begptr, cnt, colidx, b3, outp, N);
}

// Round 12
// 289.402 us; speedup vs baseline: 1.0048x; 1.0048x over previous
//
#include <hip/hip_runtime.h>
#include <hip/hip_bf16.h>
#include <type_traits>

// ---------- types ----------
typedef __attribute__((ext_vector_type(8))) short short8;   // 8 bf16 (4 VGPRs) MFMA A/B frag
typedef __attribute__((ext_vector_type(4))) float f32x4;    // MFMA C/D frag / float4
typedef __attribute__((ext_vector_type(8))) unsigned short u16x8;

static __device__ __forceinline__ unsigned short f2b(float f) {
    unsigned int v = __float_as_uint(f);
    unsigned int r = (v + 0x7FFFu + ((v >> 16) & 1u)) >> 16;   // RNE
    return (unsigned short)r;
}
static __device__ __forceinline__ float b2f(unsigned short u) {
    return __uint_as_float(((unsigned int)u) << 16);
}

// ---------- fused: all-weights transpose+cast  ||  dst-degree histogram ----------
__global__ void k_pre(const float* __restrict__ w1, unsigned short* __restrict__ t1,
                      const float* __restrict__ w2, unsigned short* __restrict__ t2,
                      const float* __restrict__ w3, unsigned short* __restrict__ t3,
                      int K1, int N1, int K2, int N2, int K3, int N3,
                      const int* __restrict__ dst, int* __restrict__ cnt, int E, int tblk) {
    if ((int)blockIdx.x < tblk) {
        int i = blockIdx.x * 256 + threadIdx.x;
        int n1 = K1 * N1, n2 = K2 * N2, n3 = K3 * N3;
        if (i < n1) {
            int k = i / N1, n = i % N1;
            t1[n * K1 + k] = f2b(w1[i]);
        } else if (i < n1 + n2) {
            int j = i - n1, k = j / N2, n = j % N2;
            t2[n * K2 + k] = f2b(w2[j]);
        } else if (i < n1 + n2 + n3) {
            int j = i - n1 - n2, k = j / N3, n = j % N3;
            t3[n * K3 + k] = f2b(w3[j]);
        }
    } else {
        int e = (blockIdx.x - tblk) * 256 + threadIdx.x;
        if (e < E) atomicAdd(&cnt[dst[e]], 1);
    }
}

// per-node segment allocation: wave-scan of (cnt+1) + one atomicAdd per wave.
// Places the self-loop at slot 0; fill[i] holds the ABSOLUTE next write slot (beg+1).
__global__ void k_assign(const int* __restrict__ cnt, int* __restrict__ begptr,
                         int* __restrict__ colidx, int* __restrict__ fill,
                         int* __restrict__ cursor, int n) {
    int i = blockIdx.x * 256 + threadIdx.x;
    int lane = threadIdx.x & 63;
    int c = (i < n) ? cnt[i] + 1 : 0;
    int s = c;  // inclusive wave scan
#pragma unroll
    for (int off = 1; off < 64; off <<= 1) {
        int v = __shfl_up(s, off);
        if (lane >= off) s += v;
    }
    int wavesum = __shfl(s, 63);
    int base = 0;
    if (lane == 63) base = atomicAdd(cursor, wavesum);
    base = __shfl(base, 63);
    int beg = base + s - c;
    if (i < n) { begptr[i] = beg; colidx[beg] = i; fill[i] = beg + 1; }
}

// ---------- MFMA GEMM body (BK=64) + fused attention logits ----------
template<int NC, typename AT>
static __device__ __forceinline__ void gemm_body(const AT* __restrict__ A,
                                                 const unsigned short* __restrict__ Bt,
                                                 unsigned short* __restrict__ H,
                                                 const float* __restrict__ asrc,
                                                 const float* __restrict__ adst,
                                                 float* __restrict__ als,
                                                 float* __restrict__ ald,
                                                 int K, int blk) {
    __shared__ unsigned short As[64][72];   // 64 k-cols + 8 pad
    __shared__ unsigned short Bs[NC][72];
    __shared__ float sps[64], spd[64];
    const int tid  = threadIdx.x;
    const int lane = tid & 63;
    const int wv   = tid >> 6;
    const int rowBase = blk * 64;
    const int quad = lane >> 4;
    const int l16  = lane & 15;
    constexpr int CG = NC / 32;             // col-frags per wave
    const int wrow = (wv & 1) * 32;
    const int wcol = (wv >> 1) * (NC / 2);
    f32x4 acc[2][CG] = {};

    if (tid < 64) { sps[tid] = 0.f; spd[tid] = 0.f; }

    const int ar = tid >> 2;                // A staging row 0..63
    const int ak = (tid & 3) * 16;          // A staging k-chunk (16 elems)

    for (int kk = 0; kk < K; kk += 64) {
        // stage A (16 elems/thread)
        if constexpr (std::is_same_v<AT, float>) {
            const float* ap = A + (size_t)(rowBase + ar) * K + kk + ak;
            f32x4 a0 = *(const f32x4*)ap;
            f32x4 a1 = *(const f32x4*)(ap + 4);
            f32x4 a2 = *(const f32x4*)(ap + 8);
            f32x4 a3 = *(const f32x4*)(ap + 12);
            short8 s0, s1;
#pragma unroll
            for (int v = 0; v < 4; v++) {
                s0[v] = (short)f2b(a0[v]); s0[4 + v] = (short)f2b(a1[v]);
                s1[v] = (short)f2b(a2[v]); s1[4 + v] = (short)f2b(a3[v]);
            }
            *(short8*)&As[ar][ak] = s0;
            *(short8*)&As[ar][ak + 8] = s1;
        } else {
            const unsigned short* ap = A + (size_t)(rowBase + ar) * K + kk + ak;
            *(short8*)&As[ar][ak]     = *(const short8*)ap;
            *(short8*)&As[ar][ak + 8] = *(const short8*)(ap + 8);
        }
        // stage B (chunks of 16)
#pragma unroll
        for (int c = tid; c < NC * 4; c += 256) {
            int br = c >> 2, bk = (c & 3) * 16;
            const unsigned short* bp = Bt + (size_t)br * K + kk + bk;
            *(short8*)&Bs[br][bk]     = *(const short8*)bp;
            *(short8*)&Bs[br][bk + 8] = *(const short8*)(bp + 8);
        }
        __syncthreads();
#pragma unroll
        for (int s = 0; s < 2; s++) {
            short8 af0 = *(const short8*)&As[wrow + l16][s * 32 + quad * 8];
            short8 af1 = *(const short8*)&As[wrow + 16 + l16][s * 32 + quad * 8];
#pragma unroll
            for (int cg = 0; cg < CG; cg++) {
                short8 bf = *(const short8*)&Bs[wcol + cg * 16 + l16][s * 32 + quad * 8];
                acc[0][cg] = __builtin_amdgcn_mfma_f32_16x16x32_bf16(af0, bf, acc[0][cg], 0, 0, 0);
                acc[1][cg] = __builtin_amdgcn_mfma_f32_16x16x32_bf16(af1, bf, acc[1][cg], 0, 0, 0);
            }
        }
        __syncthreads();
    }

    // epilogue: store bf16 H + fused partial logits
    float avs[CG], avd[CG];
#pragma unroll
    for (int cg = 0; cg < CG; cg++) {
        int gcol = wcol + cg * 16 + l16;
        avs[cg] = asrc[gcol];
        avd[cg] = adst[gcol];
#pragma unroll
        for (int rg = 0; rg < 2; rg++)
#pragma unroll
            for (int r = 0; r < 4; r++) {
                int grow = rowBase + wrow + rg * 16 + quad * 4 + r;
                H[(size_t)grow * NC + gcol] = f2b(acc[rg][cg][r]);
            }
    }
#pragma unroll
    for (int rg = 0; rg < 2; rg++)
#pragma unroll
        for (int r = 0; r < 4; r++) {
            float ps = 0.f, pd = 0.f;
#pragma unroll
            for (int cg = 0; cg < CG; cg++) { ps += acc[rg][cg][r] * avs[cg]; pd += acc[rg][cg][r] * avd[cg]; }
#pragma unroll
            for (int off = 8; off; off >>= 1) { ps += __shfl_xor(ps, off); pd += __shfl_xor(pd, off); }
            if (l16 == 0) {
                int lrow = wrow + rg * 16 + quad * 4 + r;
                atomicAdd(&sps[lrow], ps);
                atomicAdd(&spd[lrow], pd);
            }
        }
    __syncthreads();
    if (tid < 64) { als[rowBase + tid] = sps[tid]; ald[rowBase + tid] = spd[tid]; }
}

// plain GEMM kernel (layers 2,3)
template<int NC, typename AT>
__global__ __launch_bounds__(256) void k_gemm(const AT* __restrict__ A,
                                              const unsigned short* __restrict__ Bt,
                                              unsigned short* __restrict__ H,
                                              const float* __restrict__ asrc,
                                              const float* __restrict__ adst,
                                              float* __restrict__ als,
                                              float* __restrict__ ald, int K) {
    gemm_body<NC, AT>(A, Bt, H, asrc, adst, als, ald, K, blockIdx.x);
}

// fused: layer-1 GEMM || edge scatter
template<int NC, typename AT>
__global__ __launch_bounds__(256) void k_gemm_scatter(const AT* __restrict__ A,
                                                      const unsigned short* __restrict__ Bt,
                                                      unsigned short* __restrict__ H,
                                                      const float* __restrict__ asrc,
                                                      const float* __restrict__ adst,
                                                      float* __restrict__ als,
                                                      float* __restrict__ ald, int K, int gblk,
                                                      const int* __restrict__ src,
                                                      const int* __restrict__ dst,
                                                      int* __restrict__ fill,
                                                      int* __restrict__ colidx, int E) {
    if ((int)blockIdx.x < gblk) {
        gemm_body<NC, AT>(A, Bt, H, asrc, adst, als, ald, K, blockIdx.x);
    } else {
        int e = (blockIdx.x - gblk) * 256 + threadIdx.x;
        if (e < E) {
            int s = src[e], d = dst[e];
            int pos = atomicAdd(&fill[d], 1);
            colidx[pos] = s;
        }
    }
}

// ---------- edge softmax + weighted aggregation: ONE NODE PER 16-LANE QUARTER ----------
// 4 nodes/wave, 16 nodes/block. Phase 1 (exp+sum) runs for 4 nodes in parallel
// (width-16 reduce); pass 3: each quarter walks its node's edges, lanes cover
// DOUT/16 dims (32B @ 256). No cross-quarter combine — quarter owns its node.
// No max-subtraction (logits O(1), fp32-safe). [R11 x2-unroll regressed: reverted]
template<int DOUT, bool RELU, typename OutT>
__global__ __launch_bounds__(256) void k_edge(const unsigned short* __restrict__ h,
                                              const float* __restrict__ als,
                                              const float* __restrict__ ald,
                                              const int* __restrict__ begptr,
                                              const int* __restrict__ cnt,
                                              const int* __restrict__ colidx,
                                              const float* __restrict__ bias,
                                              OutT* __restrict__ out, int N) {
    int node = blockIdx.x * 16 + (threadIdx.x >> 4);
    if (node >= N) return;
    int lane  = threadIdx.x & 63;
    int l16   = lane & 15;
    int qbase = lane & 48;                  // quarter base within wave
    int beg = begptr[node];
    int deg = cnt[node] + 1;                // + self-loop
    float aldi = ald[node];

    // phase 1: exp + sum over this quarter's 16 lanes (first 16 edges cached)
    float ex_lane = 0.f;
    int   s_lane  = 0;
    float dsum = 0.f;
    for (int j = l16; j < deg; j += 16) {
        int s = colidx[beg + j];
        float e = als[s] + aldi;
        e = e > 0.f ? e : 0.2f * e;
        float ex = __expf(e);
        if (j < 16) { ex_lane = ex; s_lane = s; }
        dsum += ex;
    }
#pragma unroll
    for (int off = 8; off; off >>= 1) dsum += __shfl_xor(dsum, off, 16);
    float inv = 1.0f / dsum;
    float w_lane = ex_lane * inv;           // lanes >= deg carry 0

    // wave-uniform loop bounds (max over the wave's 4 quarters)
    int d16 = deg < 16 ? deg : 16;
    int m16 = d16;
    m16 = max(m16, __shfl_xor(m16, 16));
    m16 = max(m16, __shfl_xor(m16, 32));
    int mall = deg;
    mall = max(mall, __shfl_xor(mall, 16));
    mall = max(mall, __shfl_xor(mall, 32));

    constexpr int QV  = DOUT / 16;          // dims per lane (16 @ 256, 8 @ 128)
    constexpr int NC8 = QV / 8;             // u16x8 chunks per lane (2 or 1)
    const size_t dimOff = (size_t)l16 * QV;
    float acc[QV] = {};

    for (int t = 0; t < m16; t++) {
        float wj = __shfl(w_lane, qbase + t);   // all lanes active for the shfl
        int   sj = __shfl(s_lane, qbase + t);
        if (wj != 0.f) {                        // t >= deg -> wj == 0 -> skip load
            const unsigned short* hp = h + (size_t)sj * DOUT + dimOff;
            u16x8 c[NC8];
#pragma unroll
            for (int u = 0; u < NC8; u++) c[u] = *(const u16x8*)(hp + 8 * u);
#pragma unroll
            for (int u = 0; u < NC8; u++)
#pragma unroll
                for (int v = 0; v < 8; v++) acc[8 * u + v] += wj * b2f(c[u][v]);
        }
    }
    for (int t = 16; t < mall; t++) {           // deg>16 tail (~5% of nodes): recompute w
        if (t < deg) {
            int sj = colidx[beg + t];
            float e = als[sj] + aldi;
            e = e > 0.f ? e : 0.2f * e;
            float wj = __expf(e) * inv;
            const unsigned short* hp = h + (size_t)sj * DOUT + dimOff;
#pragma unroll
            for (int u = 0; u < NC8; u++) {
                u16x8 c = *(const u16x8*)(hp + 8 * u);
#pragma unroll
                for (int v = 0; v < 8; v++) acc[8 * u + v] += wj * b2f(c[v]);
            }
        }
    }

    // epilogue: every lane writes its QV dims of its quarter's node
    if constexpr (std::is_same_v<OutT, float>) {
        float* op = out + (size_t)node * DOUT + dimOff;
#pragma unroll
        for (int u = 0; u < QV / 4; u++) {
            f32x4 bv = *(const f32x4*)(bias + dimOff + 4 * u);
            f32x4 ov;
#pragma unroll
            for (int v = 0; v < 4; v++) {
                float val = acc[4 * u + v] + bv[v];
                if (RELU) val = fmaxf(val, 0.f);
                ov[v] = val;
            }
            *(f32x4*)(op + 4 * u) = ov;
        }
    } else {
        unsigned short* op = out + (size_t)node * DOUT + dimOff;
#pragma unroll
        for (int u = 0; u < NC8; u++) {
            u16x8 ov;
#pragma unroll
            for (int v = 0; v < 8; v++) {
                float val = acc[8 * u + v] + bias[dimOff + 8 * u + v];
                if (RELU) val = fmaxf(val, 0.f);
                ov[v] = f2b(val);
            }
            *(u16x8*)(op + 8 * u) = ov;
        }
    }
}

// ---------- launch ----------
extern "C" void kernel_launch(void* const* d_in, const int* in_sizes, int n_in,
                              void* d_out, int out_size, void* d_ws, size_t ws_size,
                              hipStream_t stream) {
    const int DIN = 128, DH = 256, DOUT = 128;
    const int N = in_sizes[0] / DIN;        // 40000
    const int E = in_sizes[1] / 2;          // 400000

    const float* x   = (const float*)d_in[0];
    const int*   ei  = (const int*)d_in[1];
    const float* W1  = (const float*)d_in[3];
    const float* as1 = (const float*)d_in[4];
    const float* ad1 = (const float*)d_in[5];
    const float* b1  = (const float*)d_in[6];
    const float* W2  = (const float*)d_in[7];
    const float* as2 = (const float*)d_in[8];
    const float* ad2 = (const float*)d_in[9];
    const float* b2  = (const float*)d_in[10];
    const float* W3  = (const float*)d_in[11];
    const float* as3 = (const float*)d_in[12];
    const float* ad3 = (const float*)d_in[13];
    const float* b3  = (const float*)d_in[14];
    float* outp = (float*)d_out;

    // workspace carve
    char* ws = (char*)d_ws;
    size_t off = 0;
    auto carve = [&](size_t bytes) { char* p = ws + off; off = (off + bytes + 255) & ~(size_t)255; return p; };
    unsigned short* hbuf = (unsigned short*)carve((size_t)N * DH * 2);  // 20 MB bf16
    unsigned short* gbuf = (unsigned short*)carve((size_t)N * DH * 2);  // 20 MB bf16
    float* als  = (float*)carve((size_t)N * 4);
    float* ald  = (float*)carve((size_t)N * 4);
    unsigned short* wt1 = (unsigned short*)carve((size_t)DIN * DH * 2);
    unsigned short* wt2 = (unsigned short*)carve((size_t)DH * DH * 2);
    unsigned short* wt3 = (unsigned short*)carve((size_t)DH * DOUT * 2);
    int* cnt    = (int*)carve((size_t)N * 4);
    int* cursor = (int*)carve(256);
    int* begptr = (int*)carve((size_t)N * 4);
    int* fill   = (int*)carve((size_t)N * 4);
    int* colidx = (int*)carve((size_t)(E + N) * 4);
    (void)ws_size; (void)n_in; (void)out_size;

    const int* e_src = ei;
    const int* e_dst = ei + E;

    // zero cnt..cursor in one async memset (allowed under graph capture)
    hipMemsetAsync(cnt, 0, (size_t)((char*)cursor - (char*)cnt) + 4, stream);

    const int tot    = DIN * DH + DH * DH + DH * DOUT;   // transpose elements
    const int tblk   = (tot + 255) / 256;
    const int eblk   = (E + 255) / 256;
    const int nblk16 = (N + 15) / 16;
    const int mblk   = N / 64;

    // transpose+cast all weights  ||  degree histogram
    k_pre<<<tblk + eblk, 256, 0, stream>>>(W1, wt1, W2, wt2, W3, wt3,
                                           DIN, DH, DH, DH, DH, DOUT,
                                           e_dst, cnt, E, tblk);
    k_assign<<<(N + 255) / 256, 256, 0, stream>>>(cnt, begptr, colidx, fill, cursor, N);

    // ---- layer 1 GEMM || edge scatter ----
    k_gemm_scatter<256, float><<<mblk + eblk, 256, 0, stream>>>(
        x, wt1, hbuf, as1, ad1, als, ald, DIN, mblk,
        e_src, e_dst, fill, colidx, E);
    k_edge<256, true, unsigned short><<<nblk16, 256, 0, stream>>>(hbuf, als, ald, begptr, cnt, colidx, b1, gbuf, N);

    // ---- layer 2: g[N,256] @ W2[256,256] ----
    k_gemm<256, unsigned short><<<mblk, 256, 0, stream>>>(gbuf, wt2, hbuf, as2, ad2, als, ald, DH);
    k_edge<256, true, unsigned short><<<nblk16, 256, 0, stream>>>(hbuf, als, ald, begptr, cnt, colidx, b2, gbuf, N);

    // ---- layer 3: g[N,256] @ W3[256,128] ----
    k_gemm<128, unsigned short><<<mblk, 256, 0, stream>>>(gbuf, wt3, hbuf, as3, ad3, als, ald, DH);
    k_edge<128, false, float><<<nblk16, 256, 0, stream>>>(hbuf, als, ald, begptr, cnt, colidx, b3, outp, N);
}